// Round 7
// baseline (289.302 us; speedup 1.0000x reference)
//
#include <hip/hip_runtime.h>
#include <math.h>

typedef __attribute__((ext_vector_type(8))) short bf16x8;
typedef __attribute__((ext_vector_type(4))) float f32x4;
typedef unsigned short u16;
typedef unsigned int u32;

#define TSEQ 2048
#define NH   16
#define DH   64
#define CDIM 1024
#define SCLQ 0.18033688011112042f  // 0.125 * log2(e): folded into Q

__device__ __forceinline__ u16 f2bf(float f) {
    union { float f; u32 u; } v; v.f = f;
    u32 r = v.u + 0x7fffu + ((v.u >> 16) & 1u);
    return (u16)(r >> 16);
}

__device__ __forceinline__ u32 cvtpk(float lo, float hi) {
    u32 r;
    asm("v_cvt_pk_bf16_f32 %0, %1, %2" : "=v"(r) : "v"(lo), "v"(hi));
    return r;
}

__device__ __forceinline__ float max3f(float a, float b, float c) {
    return fmaxf(fmaxf(a, b), c);
}

__device__ __forceinline__ void gl_lds16(const void* g, void* l) {
    __builtin_amdgcn_global_load_lds(
        (const __attribute__((address_space(1))) u32*)g,
        (__attribute__((address_space(3))) u32*)l, 16, 0, 0);
}

#define MFMA16(a, b, c) __builtin_amdgcn_mfma_f32_16x16x32_bf16(a, b, c, 0, 0, 0)

#define WAITV(n) do { asm volatile("s_waitcnt vmcnt(" #n ")" ::: "memory"); } while (0)
#define WAITL()  do { asm volatile("s_waitcnt lgkmcnt(0)" ::: "memory"); } while (0)
#define BARC()   do { __builtin_amdgcn_s_barrier(); __builtin_amdgcn_sched_barrier(0); } while (0)

// ---------------------------------------------------------------------------
// prep: merged cvt_bf16(x) + tr_w(W_qkv) + tr_w(W_out). One launch.
// ---------------------------------------------------------------------------
__global__ __launch_bounds__(256) void prep(
    const float* __restrict__ x, const float* __restrict__ Wq,
    const float* __restrict__ Wo,
    u16* __restrict__ xb, u16* __restrict__ Wqt, u16* __restrict__ Wot) {
    const int bid = blockIdx.x, tid = threadIdx.x;
    if (bid < 4096) {
        int i = (bid * 256 + tid) * 8;
        float4 a = *(const float4*)(x + i);
        float4 b = *(const float4*)(x + i + 4);
        u16 o[8] = {f2bf(a.x), f2bf(a.y), f2bf(a.z), f2bf(a.w),
                    f2bf(b.x), f2bf(b.y), f2bf(b.z), f2bf(b.w)};
        *(uint4*)(xb + i) = *(const uint4*)o;
        return;
    }
    __shared__ float tile[32][33];
    const float* Wf; u16* Wt; int K, N, n0, k0;
    if (bid < 4096 + 3072) {
        int b2 = bid - 4096;
        Wf = Wq; Wt = Wqt; K = 1024; N = 3072;
        n0 = (b2 % 96) * 32; k0 = (b2 / 96) * 32;
    } else {
        int b2 = bid - 7168;
        Wf = Wo; Wt = Wot; K = 1024; N = 1024;
        n0 = (b2 & 31) * 32; k0 = (b2 >> 5) * 32;
    }
    int tx = tid & 31, ty = tid >> 5;
#pragma unroll
    for (int r = 0; r < 4; r++)
        tile[ty + r * 8][tx] = Wf[(k0 + ty + r * 8) * N + n0 + tx];
    __syncthreads();
#pragma unroll
    for (int r = 0; r < 4; r++)
        Wt[(n0 + ty + r * 8) * K + k0 + tx] = f2bf(tile[tx][ty + r * 8]);
}

// ---------------------------------------------------------------------------
// 256x256 8-phase GEMM: C = A[M][1024] @ Bt[N][1024]^T + bias
// 512 thr (8 waves, 2M x 4N), per-wave 128x64, BK=64, LDS 128KB.
// SYNC INVARIANT (round-6 NaN fix): tile t+1's arrival is confirmed by
// WAITV(6) at the END of ph3 of tile t (after MFMA, before closing barrier);
// the barrier then makes all waves' gl_lds writes visible before ph0 of
// tile t+1 ds_reads them. Prologue: WAITV(6)+barrier confirms tile 0.
// Queue math (units of 2 loads): steady state at ph3 post-stage = 7 units;
// vmcnt(6)=3 units retires exactly {A1,B0,A0,B1}(t+1). Never 0 in loop.
// Stage slots (all write regions dead >=1 barrier earlier):
//   ph0: A1(t+1)->buf^1   ph2: B0(t+2)->buf   ph3: A0(t+2),B1(t+2)->buf
// EPI: 0 = fp32 + bias -> Of; 1 = qkv scatter (Q*SCLQ, K, V transposed).
// ---------------------------------------------------------------------------
template <int EPI>
__global__ __launch_bounds__(512, 1) void gemm256(
    const u16* __restrict__ A, const u16* __restrict__ Bt,
    const float* __restrict__ bias,
    u16* __restrict__ O0, u16* __restrict__ O1, u16* __restrict__ O2,
    float* __restrict__ Of) {
    __shared__ u16 lA[2][2][128 * 64];
    __shared__ u16 lB[2][2][128 * 64];

    const int tid = threadIdx.x;
    const int lane = tid & 63, w = tid >> 6;
    const int l15 = lane & 15, l4 = lane >> 4;
    const int wm = w >> 2, wn = w & 3;
    const int nwg = gridDim.x;
    const int wg = (blockIdx.x & 7) * (nwg >> 3) + (blockIdx.x >> 3);
    const int mi = wg & 31, ni = wg >> 5;
    const size_t mb = (size_t)mi * 256, nb = (size_t)ni * 256;
    const int KD = 1024;

    auto stA = [&](int t, int half, int buf) {
        int kb = (t & 15) * 64;
#pragma unroll
        for (int s = 0; s < 2; s++) {
            int i2 = s * 512 + tid;
            int row = i2 >> 3, g = i2 & 7;
            int gsw = g ^ (row & 7);
            gl_lds16(A + (mb + half * 128 + row) * KD + kb + gsw * 8,
                     &lA[buf][half][i2 * 8]);
        }
    };
    auto stB = [&](int t, int half, int buf) {
        int kb = (t & 15) * 64;
#pragma unroll
        for (int s = 0; s < 2; s++) {
            int i2 = s * 512 + tid;
            int row = i2 >> 3, g = i2 & 7;
            int gsw = g ^ (row & 7);
            gl_lds16(Bt + (nb + half * 128 + row) * KD + kb + gsw * 8,
                     &lB[buf][half][i2 * 8]);
        }
    };

    f32x4 zero = {0.f, 0.f, 0.f, 0.f};
    f32x4 acc[8][4];
#pragma unroll
    for (int i = 0; i < 8; i++)
#pragma unroll
        for (int j = 0; j < 4; j++) acc[i][j] = zero;

    const int hB = wn >> 1, rBb = (wn & 1) * 64;

    // prologue: tile0 {B0,A0,B1,A1} + tile1 {B0,A0,B1} = 7 units
    stB(0, 0, 0); stA(0, 0, 0); stB(0, 1, 0); stA(0, 1, 0);
    stB(1, 0, 1); stA(1, 0, 1); stB(1, 1, 1);
    WAITV(6);   // tile 0 landed (per-wave)
    BARC();     // cross-wave visibility of tile 0 before first ds_read

    bf16x8 a8[4][2], bA[2][2], bB[2][2];

    for (int t = 0; t < 16; t++) {
        const int p = t & 1, q = p ^ 1;
        // ===== ph0: A03 x B01 ; stage A1(t+1)
#pragma unroll
        for (int fm = 0; fm < 4; fm++) {
            int r = fm * 16 + l15;
            const u16* base = &lA[p][wm][r * 64];
            a8[fm][0] = *(const bf16x8*)(base + ((l4) ^ (r & 7)) * 8);
            a8[fm][1] = *(const bf16x8*)(base + ((4 + l4) ^ (r & 7)) * 8);
        }
#pragma unroll
        for (int fn = 0; fn < 2; fn++) {
            int r = rBb + fn * 16 + l15;
            const u16* base = &lB[p][hB][r * 64];
            bA[fn][0] = *(const bf16x8*)(base + ((l4) ^ (r & 7)) * 8);
            bA[fn][1] = *(const bf16x8*)(base + ((4 + l4) ^ (r & 7)) * 8);
        }
        stA(t + 1, 1, q);
        __builtin_amdgcn_s_barrier();
        WAITL();
        __builtin_amdgcn_s_setprio(1);
#pragma unroll
        for (int fm = 0; fm < 4; fm++)
#pragma unroll
            for (int fn = 0; fn < 2; fn++) {
                acc[fm][fn] = MFMA16(a8[fm][0], bA[fn][0], acc[fm][fn]);
                acc[fm][fn] = MFMA16(a8[fm][1], bA[fn][1], acc[fm][fn]);
            }
        __builtin_amdgcn_s_setprio(0);
        BARC();
        // ===== ph1: A03 x B23
#pragma unroll
        for (int fn = 0; fn < 2; fn++) {
            int r = rBb + (fn + 2) * 16 + l15;
            const u16* base = &lB[p][hB][r * 64];
            bB[fn][0] = *(const bf16x8*)(base + ((l4) ^ (r & 7)) * 8);
            bB[fn][1] = *(const bf16x8*)(base + ((4 + l4) ^ (r & 7)) * 8);
        }
        __builtin_amdgcn_s_barrier();
        WAITL();
        __builtin_amdgcn_s_setprio(1);
#pragma unroll
        for (int fm = 0; fm < 4; fm++)
#pragma unroll
            for (int fn = 0; fn < 2; fn++) {
                acc[fm][fn + 2] = MFMA16(a8[fm][0], bB[fn][0], acc[fm][fn + 2]);
                acc[fm][fn + 2] = MFMA16(a8[fm][1], bB[fn][1], acc[fm][fn + 2]);
            }
        __builtin_amdgcn_s_setprio(0);
        BARC();
        // ===== ph2: A47 x B23 ; stage B0(t+2)
#pragma unroll
        for (int fm = 0; fm < 4; fm++) {
            int r = (fm + 4) * 16 + l15;
            const u16* base = &lA[p][wm][r * 64];
            a8[fm][0] = *(const bf16x8*)(base + ((l4) ^ (r & 7)) * 8);
            a8[fm][1] = *(const bf16x8*)(base + ((4 + l4) ^ (r & 7)) * 8);
        }
        stB(t + 2, 0, p);
        __builtin_amdgcn_s_barrier();
        WAITL();
        __builtin_amdgcn_s_setprio(1);
#pragma unroll
        for (int fm = 0; fm < 4; fm++)
#pragma unroll
            for (int fn = 0; fn < 2; fn++) {
                acc[fm + 4][fn + 2] = MFMA16(a8[fm][0], bB[fn][0], acc[fm + 4][fn + 2]);
                acc[fm + 4][fn + 2] = MFMA16(a8[fm][1], bB[fn][1], acc[fm + 4][fn + 2]);
            }
        __builtin_amdgcn_s_setprio(0);
        BARC();
        // ===== ph3: A47 x B01 ; stage A0(t+2),B1(t+2); confirm tile t+1
        stA(t + 2, 0, p); stB(t + 2, 1, p);
        __builtin_amdgcn_s_barrier();
        __builtin_amdgcn_s_setprio(1);
#pragma unroll
        for (int fm = 0; fm < 4; fm++)
#pragma unroll
            for (int fn = 0; fn < 2; fn++) {
                acc[fm + 4][fn] = MFMA16(a8[fm][0], bA[fn][0], acc[fm + 4][fn]);
                acc[fm + 4][fn] = MFMA16(a8[fm][1], bA[fn][1], acc[fm + 4][fn]);
            }
        __builtin_amdgcn_s_setprio(0);
        WAITV(6);   // tile t+1 landed (per-wave), 3 units stay in flight
        BARC();     // cross-wave visibility before ph0 of tile t+1
    }
    WAITV(0);

    // epilogue
#pragma unroll
    for (int fm = 0; fm < 8; fm++)
#pragma unroll
        for (int fn = 0; fn < 4; fn++) {
            int n = (int)nb + wn * 64 + fn * 16 + l15;
            int m0 = (int)mb + wm * 128 + fm * 16 + l4 * 4;
            float bz = bias[n];
            if (EPI == 0) {
#pragma unroll
                for (int i = 0; i < 4; i++)
                    Of[(size_t)(m0 + i) * CDIM + n] = acc[fm][fn][i] + bz;
            } else {
                int which = n >> 10, hh = (n >> 6) & 15, d = n & 63;
                int b = m0 >> 11, t0 = m0 & 2047;
                if (which == 0) {
#pragma unroll
                    for (int i = 0; i < 4; i++)
                        O0[((b * NH + hh) * TSEQ + t0 + i) * DH + d] =
                            f2bf((acc[fm][fn][i] + bz) * SCLQ);
                } else if (which == 1) {
#pragma unroll
                    for (int i = 0; i < 4; i++)
                        O1[((b * NH + hh) * TSEQ + t0 + i) * DH + d] =
                            f2bf(acc[fm][fn][i] + bz);
                } else {
                    u16 ov[4];
#pragma unroll
                    for (int i = 0; i < 4; i++) ov[i] = f2bf(acc[fm][fn][i] + bz);
                    *(uint2*)&O2[((b * NH + hh) * DH + d) * TSEQ + t0] =
                        *(const uint2*)ov;
                }
            }
        }
}

// ---------------------------------------------------------------------------
// Flash attention v4 (unchanged)
// ---------------------------------------------------------------------------
__global__ __launch_bounds__(256, 4) void attn_mfma(
    const u16* __restrict__ Q, const u16* __restrict__ K,
    const u16* __restrict__ Vt, u16* __restrict__ Oc) {
    __shared__ u16 Kl[2][4096];
    __shared__ u16 Vl[2][4096];
    __shared__ u16 Pl[4096];

    const int tid = threadIdx.x;
    const int lane = tid & 63, w = tid >> 6;
    const int l15 = lane & 15, l4 = lane >> 4;
    const int bh = blockIdx.x & 63;
    const int pair = blockIdx.x >> 6;
    const int qt0 = pair, qt1 = 31 - pair;
    const int NT = qt1 + 1;

    const u16* Qb = Q + bh * TSEQ * DH;
    const u16* Kb = K + bh * TSEQ * DH;
    const u16* Vb = Vt + bh * DH * TSEQ;

    auto STAGE = [&](int kt, int p) {
#pragma unroll
        for (int r = 0; r < 2; r++) {
            int idx = r * 256 + tid;
            int row = idx >> 3, h = idx & 7;
            int hs = h ^ (row & 7);
            gl_lds16(Kb + (kt * 64 + row) * DH + hs * 8, &Kl[p][idx * 8]);
            gl_lds16(Vb + row * TSEQ + kt * 64 + hs * 8, &Vl[p][idx * 8]);
        }
    };

    const int qrow0 = qt0 * 64 + w * 16 + l15;
    const int qrow1 = qt1 * 64 + w * 16 + l15;
    bf16x8 q0a, q0b, q1a, q1b;
    {
        const u16* qp = Qb + qrow0 * DH + l4 * 8;
        q0a = *(const bf16x8*)(qp);
        q0b = *(const bf16x8*)(qp + 32);
    }
    {
        const u16* qp = Qb + qrow1 * DH + l4 * 8;
        q1a = *(const bf16x8*)(qp);
        q1b = *(const bf16x8*)(qp + 32);
    }

    f32x4 zero = {0.f, 0.f, 0.f, 0.f};
    f32x4 o0[4], o1[4];
    float m0 = -INFINITY, l0 = 0.f, m1 = -INFINITY, l1 = 0.f;
#pragma unroll
    for (int i = 0; i < 4; i++) { o0[i] = zero; o1[i] = zero; }

    auto SMPV = [&](f32x4* s, float& m_r, float& l_r, f32x4* oacc,
                    int q_row, bool domask, int kt, int p) {
        if (domask) {
#pragma unroll
            for (int c = 0; c < 4; c++)
#pragma unroll
                for (int i = 0; i < 4; i++) {
                    int kg = kt * 64 + c * 16 + l4 * 4 + i;
                    if (kg > q_row) s[c][i] = -INFINITY;
                }
        }
        float a0 = max3f(s[0][0], s[0][1], s[0][2]);
        float a1 = max3f(s[0][3], s[1][0], s[1][1]);
        float a2 = max3f(s[1][2], s[1][3], s[2][0]);
        float a3 = max3f(s[2][1], s[2][2], s[2][3]);
        float a4 = max3f(s[3][0], s[3][1], s[3][2]);
        float mx = max3f(max3f(a0, a1, a2), fmaxf(a3, a4), s[3][3]);
        mx = fmaxf(mx, __shfl_xor(mx, 16));
        mx = fmaxf(mx, __shfl_xor(mx, 32));
        if (!__all(mx <= m_r)) {
            float mnew = fmaxf(m_r, mx);
            float corr = __builtin_amdgcn_exp2f(m_r - mnew);
            l_r *= corr;
            float cr[4];
#pragma unroll
            for (int r = 0; r < 4; r++) cr[r] = __shfl(corr, l4 * 4 + r);
#pragma unroll
            for (int dg = 0; dg < 4; dg++)
#pragma unroll
                for (int r = 0; r < 4; r++) oacc[dg][r] *= cr[r];
            m_r = mnew;
        }
        float pv[16];
#pragma unroll
        for (int c = 0; c < 4; c++)
#pragma unroll
            for (int i = 0; i < 4; i++)
                pv[c * 4 + i] = __builtin_amdgcn_exp2f(s[c][i] - m_r);
        float t0 = (pv[0] + pv[1]) + (pv[2] + pv[3]);
        float t1 = (pv[4] + pv[5]) + (pv[6] + pv[7]);
        float t2 = (pv[8] + pv[9]) + (pv[10] + pv[11]);
        float t3 = (pv[12] + pv[13]) + (pv[14] + pv[15]);
        float rs = (t0 + t1) + (t2 + t3);
        rs += __shfl_xor(rs, 16);
        rs += __shfl_xor(rs, 32);
        l_r += rs;

#pragma unroll
        for (int c = 0; c < 4; c++) {
            uint2 pr;
            pr.x = cvtpk(pv[c * 4 + 0], pv[c * 4 + 1]);
            pr.y = cvtpk(pv[c * 4 + 2], pv[c * 4 + 3]);
            int g = (c << 1) + (l4 >> 1);
            int gp = g ^ (l15 & 7);
            *(uint2*)&Pl[w * 1024 + l15 * 64 + gp * 8 + ((l4 & 1) << 2)] = pr;
        }

        __builtin_amdgcn_s_setprio(1);
#pragma unroll
        for (int kk = 0; kk < 2; kk++) {
            int grp = ((kk << 2) + l4) ^ (l15 & 7);
            bf16x8 pf = *(const bf16x8*)&Pl[w * 1024 + l15 * 64 + grp * 8];
#pragma unroll
            for (int dg = 0; dg < 4; dg++) {
                int drow = (dg << 4) + l15;
                bf16x8 vf = *(const bf16x8*)(&Vl[p][drow * 64 + grp * 8]);
                oacc[dg] = MFMA16(pf, vf, oacc[dg]);
            }
        }
        __builtin_amdgcn_s_setprio(0);
    };

    STAGE(0, 0);

    for (int kt = 0; kt < NT; kt++) {
        const int p = kt & 1;
        __syncthreads();
        if (kt + 1 < NT) {
            STAGE(kt + 1, p ^ 1);
            asm volatile("s_waitcnt vmcnt(4)" ::: "memory");
        } else {
            asm volatile("s_waitcnt vmcnt(0)" ::: "memory");
        }
        __syncthreads();

        const bool act0 = (kt <= qt0);

        f32x4 s1[4], s0[4];
        __builtin_amdgcn_s_setprio(1);
#pragma unroll
        for (int c = 0; c < 4; c++) {
            int trow = c * 16 + l15;
            int swz = l15 & 7;
            bf16x8 kf0 = *(const bf16x8*)(&Kl[p][trow * 64 + (l4 ^ swz) * 8]);
            bf16x8 kf1 = *(const bf16x8*)(&Kl[p][trow * 64 + ((4 + l4) ^ swz) * 8]);
            f32x4 a = zero;
            a = MFMA16(kf0, q1a, a);
            a = MFMA16(kf1, q1b, a);
            s1[c] = a;
            if (act0) {
                f32x4 b = zero;
                b = MFMA16(kf0, q0a, b);
                b = MFMA16(kf1, q0b, b);
                s0[c] = b;
            }
        }
        __builtin_amdgcn_s_setprio(0);

        SMPV(s1, m1, l1, o1, qrow1, kt == qt1, kt, p);
        if (act0) {
            asm volatile("s_waitcnt lgkmcnt(0)" ::: "memory");
            SMPV(s0, m0, l0, o0, qrow0, kt == qt0, kt, p);
        }
    }

    const int b = bh >> 4, hh = bh & 15;
    {
        float inv[4];
#pragma unroll
        for (int r = 0; r < 4; r++) inv[r] = 1.0f / __shfl(l0, l4 * 4 + r);
        int tb = qt0 * 64 + w * 16 + l4 * 4;
#pragma unroll
        for (int r = 0; r < 4; r++)
#pragma unroll
            for (int dg = 0; dg < 4; dg++)
                Oc[(b * TSEQ + tb + r) * CDIM + hh * DH + (dg << 4) + l15] =
                    f2bf(o0[dg][r] * inv[r]);
    }
    {
        float inv[4];
#pragma unroll
        for (int r = 0; r < 4; r++) inv[r] = 1.0f / __shfl(l1, l4 * 4 + r);
        int tb = qt1 * 64 + w * 16 + l4 * 4;
#pragma unroll
        for (int r = 0; r < 4; r++)
#pragma unroll
            for (int dg = 0; dg < 4; dg++)
                Oc[(b * TSEQ + tb + r) * CDIM + hh * DH + (dg << 4) + l15] =
                    f2bf(o1[dg][r] * inv[r]);
    }
}

extern "C" void kernel_launch(void* const* d_in, const int* in_sizes, int n_in,
                              void* d_out, int out_size, void* d_ws, size_t ws_size,
                              hipStream_t stream) {
    const float* x     = (const float*)d_in[0];
    const float* W_qkv = (const float*)d_in[1];
    const float* b_qkv = (const float*)d_in[2];
    const float* W_out = (const float*)d_in[3];
    const float* b_out = (const float*)d_in[4];
    float* out = (float*)d_out;

    u16* xb  = (u16*)d_ws;            // 8192*1024
    u16* Wqt = xb  + 8388608;         // 3072*1024
    u16* Wot = Wqt + 3145728;         // 1024*1024
    u16* Qw  = Wot + 1048576;         // (pre-scaled by SCLQ)
    u16* Kw  = Qw  + 8388608;
    u16* Vtw = Kw  + 8388608;         // V transposed [bh][d][t]
    u16* Ocw = Vtw + 8388608;

    prep<<<8192, 256, 0, stream>>>(x, W_qkv, W_out, xb, Wqt, Wot);
    gemm256<1><<<384, 512, 0, stream>>>(xb, Wqt, b_qkv, Qw, Kw, Vtw, nullptr);
    attn_mfma<<<1024, 256, 0, stream>>>(Qw, Kw, Vtw, Ocw);
    gemm256<0><<<128, 512, 0, stream>>>(Ocw, Wot, b_out, nullptr, nullptr, nullptr, out);
}

// Round 8
// 263.280 us; speedup vs baseline: 1.0988x; 1.0988x over previous
//
#include <hip/hip_runtime.h>
#include <math.h>

typedef __attribute__((ext_vector_type(8))) short bf16x8;
typedef __attribute__((ext_vector_type(4))) float f32x4;
typedef unsigned short u16;
typedef unsigned int u32;

#define TSEQ 2048
#define NH   16
#define DH   64
#define CDIM 1024
#define SCLQ 0.18033688011112042f  // 0.125 * log2(e): folded into Q

__device__ __forceinline__ u16 f2bf(float f) {
    union { float f; u32 u; } v; v.f = f;
    u32 r = v.u + 0x7fffu + ((v.u >> 16) & 1u);
    return (u16)(r >> 16);
}

__device__ __forceinline__ u32 cvtpk(float lo, float hi) {
    u32 r;
    asm("v_cvt_pk_bf16_f32 %0, %1, %2" : "=v"(r) : "v"(lo), "v"(hi));
    return r;
}

__device__ __forceinline__ float max3f(float a, float b, float c) {
    return fmaxf(fmaxf(a, b), c);
}

__device__ __forceinline__ void gl_lds16(const void* g, void* l) {
    __builtin_amdgcn_global_load_lds(
        (const __attribute__((address_space(1))) u32*)g,
        (__attribute__((address_space(3))) u32*)l, 16, 0, 0);
}

#define MFMA16(a, b, c) __builtin_amdgcn_mfma_f32_16x16x32_bf16(a, b, c, 0, 0, 0)

#define WAITV(n) do { asm volatile("s_waitcnt vmcnt(" #n ")" ::: "memory"); } while (0)
#define WAITL()  do { asm volatile("s_waitcnt lgkmcnt(0)" ::: "memory"); \
                      __builtin_amdgcn_sched_barrier(0); } while (0)
#define BARC()   do { __builtin_amdgcn_s_barrier(); __builtin_amdgcn_sched_barrier(0); } while (0)

// granule swizzle for 64B rows (4x16B granules): bijective per row, spreads
// rows r, r+4, r+8, r+12 (same bank base) over distinct granules -> <=2-way.
__device__ __forceinline__ int swz4(int r) { return (r & 3) ^ ((r >> 2) & 3); }

// ---------------------------------------------------------------------------
// prep: merged cvt_bf16(x) + tr_w(W_qkv) + tr_w(W_out). One launch.
// ---------------------------------------------------------------------------
__global__ __launch_bounds__(256) void prep(
    const float* __restrict__ x, const float* __restrict__ Wq,
    const float* __restrict__ Wo,
    u16* __restrict__ xb, u16* __restrict__ Wqt, u16* __restrict__ Wot) {
    const int bid = blockIdx.x, tid = threadIdx.x;
    if (bid < 4096) {
        int i = (bid * 256 + tid) * 8;
        float4 a = *(const float4*)(x + i);
        float4 b = *(const float4*)(x + i + 4);
        u16 o[8] = {f2bf(a.x), f2bf(a.y), f2bf(a.z), f2bf(a.w),
                    f2bf(b.x), f2bf(b.y), f2bf(b.z), f2bf(b.w)};
        *(uint4*)(xb + i) = *(const uint4*)o;
        return;
    }
    __shared__ float tile[32][33];
    const float* Wf; u16* Wt; int K, N, n0, k0;
    if (bid < 4096 + 3072) {
        int b2 = bid - 4096;
        Wf = Wq; Wt = Wqt; K = 1024; N = 3072;
        n0 = (b2 % 96) * 32; k0 = (b2 / 96) * 32;
    } else {
        int b2 = bid - 7168;
        Wf = Wo; Wt = Wot; K = 1024; N = 1024;
        n0 = (b2 & 31) * 32; k0 = (b2 >> 5) * 32;
    }
    int tx = tid & 31, ty = tid >> 5;
#pragma unroll
    for (int r = 0; r < 4; r++)
        tile[ty + r * 8][tx] = Wf[(k0 + ty + r * 8) * N + n0 + tx];
    __syncthreads();
#pragma unroll
    for (int r = 0; r < 4; r++)
        Wt[(n0 + ty + r * 8) * K + k0 + tx] = f2bf(tile[tx][ty + r * 8]);
}

// ---------------------------------------------------------------------------
// Ring-3 GEMM: C[M][N] = A[M][1024] @ Bt[N][1024]^T + bias
// BM=128, BN=256, BK=32, 512 thr (8 waves 2Mx4N, per-wave 64x64).
// LDS = ring-3 {A 8KB + B 16KB} = 72KB -> 2 blocks/CU (concurrency is the
// point: staging blend-rate scales with resident blocks; r2 9 TB/s @3-4/CU
// vs r7 4.2 @1/CU). ONE barrier + ONE lgkm wait per K-tile.
// Schedule per tile t (buf t%3): stage(ts=min(t+2,31) -> buf (t+2)%3);
// ds_read 8 frags of tile t; WAITV(3); WAITL; BARC; 16 MFMA.
// FIFO proof: at WAITV(3) outstanding <= {t+1 batch, t+2 batch} = 6 loads
// (3/tile: A=1,B=2); retiring to 3 retires exactly the t+1 batch -> barrier
// publishes t+1 to all waves. Never vmcnt(0) in loop. Races: stage target
// buf held tile t-1, whose reads completed before WAITL(t-1) < BARC(t-1) <
// this stage issue; tail re-stage of tile 31 lands only in dead bufs.
// EPI: 0 = fp32 + bias -> Of; 1 = qkv scatter (Q*SCLQ, K, V transposed).
// ---------------------------------------------------------------------------
template <int EPI>
__global__ __launch_bounds__(512, 4) void gemm_r3(
    const u16* __restrict__ A, const u16* __restrict__ Bt,
    const float* __restrict__ bias,
    u16* __restrict__ O0, u16* __restrict__ O1, u16* __restrict__ O2,
    float* __restrict__ Of) {
    __shared__ u16 lA[3][128 * 32];   // 24 KB
    __shared__ u16 lB[3][256 * 32];   // 48 KB

    const int tid = threadIdx.x;
    const int lane = tid & 63, w = tid >> 6;
    const int l15 = lane & 15, l4 = lane >> 4;
    const int wm = w >> 2, wn = w & 3;
    const int nwg = gridDim.x;
    const int wg = (blockIdx.x & 7) * (nwg >> 3) + (blockIdx.x >> 3);
    const int mi = wg & 63, ni = wg >> 6;
    const size_t mb = (size_t)mi * 128, nb = (size_t)ni * 256;
    const int KD = 1024;

    // stage: linear LDS dest, inverse-swizzled global source (both-sides rule)
    const int srowA = tid >> 2, sgA = tid & 3;
    const int sgswA = sgA ^ swz4(srowA);
    auto stA = [&](int ts, int buf) {
        gl_lds16(A + (mb + srowA) * KD + ts * 32 + sgswA * 8,
                 &lA[buf][tid * 8]);
    };
    auto stB = [&](int ts, int buf) {
#pragma unroll
        for (int s = 0; s < 2; s++) {
            int idx = s * 512 + tid;
            int row = idx >> 2, g = idx & 3;
            gl_lds16(Bt + (nb + row) * KD + ts * 32 + (g ^ swz4(row)) * 8,
                     &lB[buf][idx * 8]);
        }
    };

    f32x4 zero = {0.f, 0.f, 0.f, 0.f};
    f32x4 acc[4][4];
#pragma unroll
    for (int i = 0; i < 4; i++)
#pragma unroll
        for (int j = 0; j < 4; j++) acc[i][j] = zero;

    // per-frag read offsets (granule p = l4 ^ swz4(row))
    int aOff[4], bOff[4];
#pragma unroll
    for (int f = 0; f < 4; f++) {
        int ra = wm * 64 + f * 16 + l15;
        aOff[f] = (ra << 5) + (l4 ^ swz4(ra)) * 8;
        int rb = wn * 64 + f * 16 + l15;
        bOff[f] = (rb << 5) + (l4 ^ swz4(rb)) * 8;
    }

    // prologue: tiles 0,1 (A,B each) = 6 loads; confirm tile 0; publish
    stA(0, 0); stB(0, 0);
    stA(1, 1); stB(1, 1);
    WAITV(3);
    BARC();

#pragma unroll
    for (int t = 0; t < 32; t++) {
        const int buf = t % 3;
        const int bs = (t + 2) % 3;
        const int ts = (t + 2 > 31) ? 31 : t + 2;  // tail re-stage: dead bufs only
        stA(ts, bs); stB(ts, bs);

        bf16x8 a8[4], b8[4];
#pragma unroll
        for (int f = 0; f < 4; f++) a8[f] = *(const bf16x8*)(&lA[buf][aOff[f]]);
#pragma unroll
        for (int f = 0; f < 4; f++) b8[f] = *(const bf16x8*)(&lB[buf][bOff[f]]);

        WAITV(3);   // t+1 batch retired (per-wave)
        WAITL();    // this wave's frag reads complete BEFORE the barrier
        BARC();     // publish: t+1 visible, tile-t reads retired block-wide

        __builtin_amdgcn_s_setprio(1);
#pragma unroll
        for (int fm = 0; fm < 4; fm++)
#pragma unroll
            for (int fn = 0; fn < 4; fn++)
                acc[fm][fn] = MFMA16(a8[fm], b8[fn], acc[fm][fn]);
        __builtin_amdgcn_s_setprio(0);
    }
    WAITV(0);  // drain tail dummy stages before kernel end

    // epilogue (identical geometry to r5's verified version)
#pragma unroll
    for (int fm = 0; fm < 4; fm++)
#pragma unroll
        for (int fn = 0; fn < 4; fn++) {
            int n = (int)nb + wn * 64 + fn * 16 + l15;
            int m0 = (int)mb + wm * 64 + fm * 16 + l4 * 4;
            float bz = bias[n];
            if (EPI == 0) {
#pragma unroll
                for (int i = 0; i < 4; i++)
                    Of[(size_t)(m0 + i) * CDIM + n] = acc[fm][fn][i] + bz;
            } else {
                int which = n >> 10, hh = (n >> 6) & 15, d = n & 63;
                int b = m0 >> 11, t0 = m0 & 2047;
                if (which == 0) {
#pragma unroll
                    for (int i = 0; i < 4; i++)
                        O0[((b * NH + hh) * TSEQ + t0 + i) * DH + d] =
                            f2bf((acc[fm][fn][i] + bz) * SCLQ);
                } else if (which == 1) {
#pragma unroll
                    for (int i = 0; i < 4; i++)
                        O1[((b * NH + hh) * TSEQ + t0 + i) * DH + d] =
                            f2bf(acc[fm][fn][i] + bz);
                } else {
                    u16 ov[4];
#pragma unroll
                    for (int i = 0; i < 4; i++) ov[i] = f2bf(acc[fm][fn][i] + bz);
                    *(uint2*)&O2[((b * NH + hh) * DH + d) * TSEQ + t0] =
                        *(const uint2*)ov;
                }
            }
        }
}

// ---------------------------------------------------------------------------
// Flash attention v4 (unchanged from r7)
// ---------------------------------------------------------------------------
__global__ __launch_bounds__(256, 4) void attn_mfma(
    const u16* __restrict__ Q, const u16* __restrict__ K,
    const u16* __restrict__ Vt, u16* __restrict__ Oc) {
    __shared__ u16 Kl[2][4096];
    __shared__ u16 Vl[2][4096];
    __shared__ u16 Pl[4096];

    const int tid = threadIdx.x;
    const int lane = tid & 63, w = tid >> 6;
    const int l15 = lane & 15, l4 = lane >> 4;
    const int bh = blockIdx.x & 63;
    const int pair = blockIdx.x >> 6;
    const int qt0 = pair, qt1 = 31 - pair;
    const int NT = qt1 + 1;

    const u16* Qb = Q + bh * TSEQ * DH;
    const u16* Kb = K + bh * TSEQ * DH;
    const u16* Vb = Vt + bh * DH * TSEQ;

    auto STAGE = [&](int kt, int p) {
#pragma unroll
        for (int r = 0; r < 2; r++) {
            int idx = r * 256 + tid;
            int row = idx >> 3, h = idx & 7;
            int hs = h ^ (row & 7);
            gl_lds16(Kb + (kt * 64 + row) * DH + hs * 8, &Kl[p][idx * 8]);
            gl_lds16(Vb + row * TSEQ + kt * 64 + hs * 8, &Vl[p][idx * 8]);
        }
    };

    const int qrow0 = qt0 * 64 + w * 16 + l15;
    const int qrow1 = qt1 * 64 + w * 16 + l15;
    bf16x8 q0a, q0b, q1a, q1b;
    {
        const u16* qp = Qb + qrow0 * DH + l4 * 8;
        q0a = *(const bf16x8*)(qp);
        q0b = *(const bf16x8*)(qp + 32);
    }
    {
        const u16* qp = Qb + qrow1 * DH + l4 * 8;
        q1a = *(const bf16x8*)(qp);
        q1b = *(const bf16x8*)(qp + 32);
    }

    f32x4 zero = {0.f, 0.f, 0.f, 0.f};
    f32x4 o0[4], o1[4];
    float m0 = -INFINITY, l0 = 0.f, m1 = -INFINITY, l1 = 0.f;
#pragma unroll
    for (int i = 0; i < 4; i++) { o0[i] = zero; o1[i] = zero; }

    auto SMPV = [&](f32x4* s, float& m_r, float& l_r, f32x4* oacc,
                    int q_row, bool domask, int kt, int p) {
        if (domask) {
#pragma unroll
            for (int c = 0; c < 4; c++)
#pragma unroll
                for (int i = 0; i < 4; i++) {
                    int kg = kt * 64 + c * 16 + l4 * 4 + i;
                    if (kg > q_row) s[c][i] = -INFINITY;
                }
        }
        float a0 = max3f(s[0][0], s[0][1], s[0][2]);
        float a1 = max3f(s[0][3], s[1][0], s[1][1]);
        float a2 = max3f(s[1][2], s[1][3], s[2][0]);
        float a3 = max3f(s[2][1], s[2][2], s[2][3]);
        float a4 = max3f(s[3][0], s[3][1], s[3][2]);
        float mx = max3f(max3f(a0, a1, a2), fmaxf(a3, a4), s[3][3]);
        mx = fmaxf(mx, __shfl_xor(mx, 16));
        mx = fmaxf(mx, __shfl_xor(mx, 32));
        if (!__all(mx <= m_r)) {
            float mnew = fmaxf(m_r, mx);
            float corr = __builtin_amdgcn_exp2f(m_r - mnew);
            l_r *= corr;
            float cr[4];
#pragma unroll
            for (int r = 0; r < 4; r++) cr[r] = __shfl(corr, l4 * 4 + r);
#pragma unroll
            for (int dg = 0; dg < 4; dg++)
#pragma unroll
                for (int r = 0; r < 4; r++) oacc[dg][r] *= cr[r];
            m_r = mnew;
        }
        float pv[16];
#pragma unroll
        for (int c = 0; c < 4; c++)
#pragma unroll
            for (int i = 0; i < 4; i++)
                pv[c * 4 + i] = __builtin_amdgcn_exp2f(s[c][i] - m_r);
        float t0 = (pv[0] + pv[1]) + (pv[2] + pv[3]);
        float t1 = (pv[4] + pv[5]) + (pv[6] + pv[7]);
        float t2 = (pv[8] + pv[9]) + (pv[10] + pv[11]);
        float t3 = (pv[12] + pv[13]) + (pv[14] + pv[15]);
        float rs = (t0 + t1) + (t2 + t3);
        rs += __shfl_xor(rs, 16);
        rs += __shfl_xor(rs, 32);
        l_r += rs;

#pragma unroll
        for (int c = 0; c < 4; c++) {
            uint2 pr;
            pr.x = cvtpk(pv[c * 4 + 0], pv[c * 4 + 1]);
            pr.y = cvtpk(pv[c * 4 + 2], pv[c * 4 + 3]);
            int g = (c << 1) + (l4 >> 1);
            int gp = g ^ (l15 & 7);
            *(uint2*)&Pl[w * 1024 + l15 * 64 + gp * 8 + ((l4 & 1) << 2)] = pr;
        }

        __builtin_amdgcn_s_setprio(1);
#pragma unroll
        for (int kk = 0; kk < 2; kk++) {
            int grp = ((kk << 2) + l4) ^ (l15 & 7);
            bf16x8 pf = *(const bf16x8*)&Pl[w * 1024 + l15 * 64 + grp * 8];
#pragma unroll
            for (int dg = 0; dg < 4; dg++) {
                int drow = (dg << 4) + l15;
                bf16x8 vf = *(const bf16x8*)(&Vl[p][drow * 64 + grp * 8]);
                oacc[dg] = MFMA16(pf, vf, oacc[dg]);
            }
        }
        __builtin_amdgcn_s_setprio(0);
    };

    STAGE(0, 0);

    for (int kt = 0; kt < NT; kt++) {
        const int p = kt & 1;
        __syncthreads();
        if (kt + 1 < NT) {
            STAGE(kt + 1, p ^ 1);
            asm volatile("s_waitcnt vmcnt(4)" ::: "memory");
        } else {
            asm volatile("s_waitcnt vmcnt(0)" ::: "memory");
        }
        __syncthreads();

        const bool act0 = (kt <= qt0);

        f32x4 s1[4], s0[4];
        __builtin_amdgcn_s_setprio(1);
#pragma unroll
        for (int c = 0; c < 4; c++) {
            int trow = c * 16 + l15;
            int swz = l15 & 7;
            bf16x8 kf0 = *(const bf16x8*)(&Kl[p][trow * 64 + (l4 ^ swz) * 8]);
            bf16x8 kf1 = *(const bf16x8*)(&Kl[p][trow * 64 + ((4 + l4) ^ swz) * 8]);
            f32x4 a = zero;
            a = MFMA16(kf0, q1a, a);
            a = MFMA16(kf1, q1b, a);
            s1[c] = a;
            if (act0) {
                f32x4 b = zero;
                b = MFMA16(kf0, q0a, b);
                b = MFMA16(kf1, q0b, b);
                s0[c] = b;
            }
        }
        __builtin_amdgcn_s_setprio(0);

        SMPV(s1, m1, l1, o1, qrow1, kt == qt1, kt, p);
        if (act0) {
            asm volatile("s_waitcnt lgkmcnt(0)" ::: "memory");
            SMPV(s0, m0, l0, o0, qrow0, kt == qt0, kt, p);
        }
    }

    const int b = bh >> 4, hh = bh & 15;
    {
        float inv[4];
#pragma unroll
        for (int r = 0; r < 4; r++) inv[r] = 1.0f / __shfl(l0, l4 * 4 + r);
        int tb = qt0 * 64 + w * 16 + l4 * 4;
#pragma unroll
        for (int r = 0; r < 4; r++)
#pragma unroll
            for (int dg = 0; dg < 4; dg++)
                Oc[(b * TSEQ + tb + r) * CDIM + hh * DH + (dg << 4) + l15] =
                    f2bf(o0[dg][r] * inv[r]);
    }
    {
        float inv[4];
#pragma unroll
        for (int r = 0; r < 4; r++) inv[r] = 1.0f / __shfl(l1, l4 * 4 + r);
        int tb = qt1 * 64 + w * 16 + l4 * 4;
#pragma unroll
        for (int r = 0; r < 4; r++)
#pragma unroll
            for (int dg = 0; dg < 4; dg++)
                Oc[(b * TSEQ + tb + r) * CDIM + hh * DH + (dg << 4) + l15] =
                    f2bf(o1[dg][r] * inv[r]);
    }
}

extern "C" void kernel_launch(void* const* d_in, const int* in_sizes, int n_in,
                              void* d_out, int out_size, void* d_ws, size_t ws_size,
                              hipStream_t stream) {
    const float* x     = (const float*)d_in[0];
    const float* W_qkv = (const float*)d_in[1];
    const float* b_qkv = (const float*)d_in[2];
    const float* W_out = (const float*)d_in[3];
    const float* b_out = (const float*)d_in[4];
    float* out = (float*)d_out;

    u16* xb  = (u16*)d_ws;            // 8192*1024
    u16* Wqt = xb  + 8388608;         // 3072*1024
    u16* Wot = Wqt + 3145728;         // 1024*1024
    u16* Qw  = Wot + 1048576;         // (pre-scaled by SCLQ)
    u16* Kw  = Qw  + 8388608;
    u16* Vtw = Kw  + 8388608;         // V transposed [bh][d][t]
    u16* Ocw = Vtw + 8388608;

    prep<<<8192, 256, 0, stream>>>(x, W_qkv, W_out, xb, Wqt, Wot);
    gemm_r3<1><<<768, 512, 0, stream>>>(xb, Wqt, b_qkv, Qw, Kw, Vtw, nullptr);
    attn_mfma<<<1024, 256, 0, stream>>>(Qw, Kw, Vtw, Ocw);
    gemm_r3<0><<<256, 512, 0, stream>>>(Ocw, Wot, b_out, nullptr, nullptr, nullptr, out);
}